// Round 1
// baseline (179.078 us; speedup 1.0000x reference)
//
#include <hip/hip_runtime.h>
#include <hip/hip_bf16.h>

typedef __attribute__((ext_vector_type(4))) float f32x4;
typedef __attribute__((ext_vector_type(8))) short s16x8;

__device__ inline short to_bf16(float f) {
  union { float f; unsigned u; } c; c.f = f;
  unsigned u = c.u;
  u += 0x7fffu + ((u >> 16) & 1u);   // round-to-nearest-even
  return (short)(u >> 16);
}

__device__ inline s16x8 pack8(f32x4 a, f32x4 b) {
  s16x8 r;
  r[0] = to_bf16(a[0]); r[1] = to_bf16(a[1]); r[2] = to_bf16(a[2]); r[3] = to_bf16(a[3]);
  r[4] = to_bf16(b[0]); r[5] = to_bf16(b[1]); r[6] = to_bf16(b[2]); r[7] = to_bf16(b[3]);
  return r;
}

#define BPW 4   // blocks per workgroup; 512 wgs * 4 = 2048 blocks total

__global__ __launch_bounds__(256, 2)
void sparse_deconv_kernel(const float* __restrict__ in, const float* __restrict__ mask,
                          const float* __restrict__ kern, const float* __restrict__ bias,
                          float* __restrict__ out) {
  const int tid = threadIdx.x;
  const int w  = tid >> 6;   // wave 0..3
  const int l  = tid & 63;   // lane
  const int lm = l & 15;
  const int lg = l >> 4;

  // ---- Weights as MFMA A-fragments: m = q*64+f (16 m-tiles), k = c (2 k-frags).
  // A[m][c] = kern[m*64 + c]  (kernel [kh,kw,F,C] flat == [256][64] row-major).
  s16x8 wf[16][2];
#pragma unroll
  for (int mt = 0; mt < 16; ++mt) {
#pragma unroll
    for (int kf = 0; kf < 2; ++kf) {
      const float* p = kern + ((mt * 16 + lm) * 64 + kf * 32 + lg * 8);
      f32x4 a = *(const f32x4*)p;
      f32x4 b = *(const f32x4*)(p + 4);
      wf[mt][kf] = pack8(a, b);
    }
  }

  // bias fragments: bv[ft][j] = bias[ft*16 + lg*4 + j]  (matches C/D row layout)
  f32x4 bv[4];
#pragma unroll
  for (int i = 0; i < 4; ++i)
    bv[i] = *(const f32x4*)(bias + i * 16 + lg * 4);

  for (int kb = 0; kb < BPW; ++kb) {
    const int b  = blockIdx.x * BPW + kb;   // 0..2047
    const int n  = b >> 8;
    const int by = (b >> 4) & 15;
    const int bx = b & 15;

    // ---- per-block mask max (redundant per wave; no barriers needed)
    const float* mp = mask + ((n * 256 + by * 16) * 256 + bx * 16);
    float mv = 0.0f;  // mask values are uniform[0,1)
#pragma unroll
    for (int i = 0; i < 4; ++i) {
      const int idx = i * 64 + l;
      mv = fmaxf(mv, mp[(idx >> 4) * 256 + (idx & 15)]);
    }
#pragma unroll
    for (int off = 32; off; off >>= 1)
      mv = fmaxf(mv, __shfl_xor(mv, off));
    const bool active = mv > 0.5f;

    // ---- 4 rows per wave; each iteration: 16 pixels -> 16x2 MFMAs -> 256 outs/pixel
#pragma unroll
    for (int i = 0; i < 4; ++i) {
      const int y  = w * 4 + i;
      const int gy = by * 16 + y;
      const int gx = bx * 16 + lm;         // this lane's pixel (B-operand col)
      float* o0 = out + (((n * 512 + 2 * gy) * 512) + 2 * gx) * 64;  // ky = 0
      float* o1 = o0 + 512 * 64;                                     // ky = 1

      if (active) {
        // B[k=c][n=pixel]: 8 consecutive channels per lane, same k-convention as A.
        const float* ip = in + ((n * 256 + gy) * 256 + gx) * 64 + lg * 8;
        f32x4 x0 = *(const f32x4*)ip;
        f32x4 x1 = *(const f32x4*)(ip + 4);
        f32x4 x2 = *(const f32x4*)(ip + 32);
        f32x4 x3 = *(const f32x4*)(ip + 36);
        s16x8 xf0 = pack8(x0, x1);
        s16x8 xf1 = pack8(x2, x3);
#pragma unroll
        for (int mt = 0; mt < 16; ++mt) {
          f32x4 acc = {0.f, 0.f, 0.f, 0.f};
          acc = __builtin_amdgcn_mfma_f32_16x16x32_bf16(wf[mt][0], xf0, acc, 0, 0, 0);
          acc = __builtin_amdgcn_mfma_f32_16x16x32_bf16(wf[mt][1], xf1, acc, 0, 0, 0);
          const int ft = mt & 3;          // f-tile within q
          const int kx = (mt >> 2) & 1;
          const int ky = mt >> 3;
          f32x4 res = acc + bv[ft];
          // lane holds f = ft*16 + lg*4 + j (j=0..3), contiguous -> 16B store
          float* dst = (ky ? o1 : o0) + kx * 64 + ft * 16 + lg * 4;
          *(f32x4*)dst = res;
        }
      } else {
        const f32x4 z = {0.f, 0.f, 0.f, 0.f};
#pragma unroll
        for (int mt = 0; mt < 16; ++mt) {
          const int ft = mt & 3;
          const int kx = (mt >> 2) & 1;
          const int ky = mt >> 3;
          float* dst = (ky ? o1 : o0) + kx * 64 + ft * 16 + lg * 4;
          *(f32x4*)dst = z;
        }
      }
    }
  }
}

extern "C" void kernel_launch(void* const* d_in, const int* in_sizes, int n_in,
                              void* d_out, int out_size, void* d_ws, size_t ws_size,
                              hipStream_t stream) {
  const float* in   = (const float*)d_in[0];
  const float* mask = (const float*)d_in[1];
  const float* kern = (const float*)d_in[2];
  const float* bias = (const float*)d_in[3];
  float* out = (float*)d_out;
  dim3 grid(512), block(256);
  hipLaunchKernelGGL(sparse_deconv_kernel, grid, block, 0, stream,
                     in, mask, kern, bias, out);
}